// Round 2
// baseline (151.602 us; speedup 1.0000x reference)
//
#include <hip/hip_runtime.h>

// Problem constants (match reference): B=8, T=16, H=512, W=512
#define HH 512
#define WW 512
#define TT 16

typedef float vf4 __attribute__((ext_vector_type(4)));
typedef float vf2 __attribute__((ext_vector_type(2)));

__device__ __forceinline__ float warp_one(const float* __restrict__ im,
                                          float fi, float fj,
                                          float ux, float uy) {
    // si = i - U[...,0]; sj = j - U[...,1]
    float si = fi - ux;
    float sj = fj - uy;
    // i0 = clip(floor(si).astype(int32), 0, H-1)  (clip AFTER int conversion)
    int i0 = (int)floorf(si);
    int j0 = (int)floorf(sj);
    i0 = min(max(i0, 0), HH - 1);
    j0 = min(max(j0, 0), WW - 1);
    int i1 = min(i0 + 1, HH - 1);
    int j1 = min(j0 + 1, WW - 1);
    // fractional weights from CLIPPED corners (matches reference)
    float di = si - (float)i0;
    float dj = sj - (float)j0;
    float f00 = im[i0 * WW + j0];
    float f01 = im[i0 * WW + j1];
    float f10 = im[i1 * WW + j0];
    float f11 = im[i1 * WW + j1];
    float f0 = f00 + (f01 - f00) * dj;
    float f1 = f10 + (f11 - f10) * dj;
    return f0 + (f1 - f0) * di;
}

__global__ __launch_bounds__(256) void SpatialWarp_kernel(
    const float* __restrict__ img,   // (B,H,W)
    const float* __restrict__ U,     // (B,T,H,W,2)
    float* __restrict__ out,         // (B,T,H,W)
    long long npairs)                // B*T*H*W / 2
{
    long long stride = (long long)gridDim.x * blockDim.x;
    for (long long k = (long long)blockIdx.x * blockDim.x + threadIdx.x;
         k < npairs; k += stride) {
        long long n = k << 1;                   // first pixel index of the pair
        int j  = (int)(n & (WW - 1));           // W = 512 = 2^9
        int i  = (int)((n >> 9) & (HH - 1));    // H = 512 = 2^9
        int bt = (int)(n >> 18);
        int b  = bt >> 4;                       // T = 16 = 2^4
        const float* im = img + (size_t)b * (HH * WW);

        // U for pixels n and n+1: 4 consecutive floats (di0,dj0,di1,dj1)
        vf4 u = __builtin_nontemporal_load(reinterpret_cast<const vf4*>(U) + k);

        float r0 = warp_one(im, (float)i, (float)j,       u.x, u.y);
        float r1 = warp_one(im, (float)i, (float)(j + 1), u.z, u.w);

        vf2 rv;
        rv.x = r0; rv.y = r1;
        __builtin_nontemporal_store(rv, reinterpret_cast<vf2*>(out) + k);
    }
}

extern "C" void kernel_launch(void* const* d_in, const int* in_sizes, int n_in,
                              void* d_out, int out_size, void* d_ws, size_t ws_size,
                              hipStream_t stream) {
    const float* img = (const float*)d_in[0];   // (8,512,512) fp32
    const float* U   = (const float*)d_in[1];   // (8,16,512,512,2) fp32
    float* out = (float*)d_out;                 // (8,16,512,512) fp32

    long long total  = (long long)out_size;     // B*T*H*W = 2^25
    long long npairs = total >> 1;

    dim3 block(256);
    dim3 grid(4096);                            // grid-stride; 2 pixels/thread/iter
    hipLaunchKernelGGL(SpatialWarp_kernel, grid, block, 0, stream,
                       img, U, out, npairs);
}

// Round 3
// 88.369 us; speedup vs baseline: 1.7156x; 1.7156x over previous
//
#include <hip/hip_runtime.h>

// B=8, T=16, H=512, W=512
#define HH 512
#define WW 512
#define TT 16
#define NROWS 16      // staged img rows per block: clamp(i-7 .. i+8)
#define SLOT_OFF 7

typedef float vf4 __attribute__((ext_vector_type(4)));
typedef float vf2 __attribute__((ext_vector_type(2)));

__device__ __forceinline__ float warp_one(const float* __restrict__ lds,
                                          const float* __restrict__ im,
                                          int ic, float fi, float fj,
                                          float ux, float uy) {
    float si = fi - ux;
    float sj = fj - uy;
    int i0 = (int)floorf(si);
    int j0 = (int)floorf(sj);
    i0 = min(max(i0, 0), HH - 1);
    j0 = min(max(j0, 0), WW - 1);
    int i1 = min(i0 + 1, HH - 1);
    int j1 = min(j0 + 1, WW - 1);
    // fractional weights from CLIPPED corners (matches reference)
    float di = si - (float)i0;
    float dj = sj - (float)j0;
    int s0 = i0 - ic + SLOT_OFF;
    int s1 = i1 - ic + SLOT_OFF;
    float f00, f01, f10, f11;
    if (((unsigned)s0 < NROWS) & ((unsigned)s1 < NROWS)) {
        // fast path: staged rows in LDS (P ~ 1 - 1e-12 for N(0,1) disp)
        f00 = lds[s0 * WW + j0];
        f01 = lds[s0 * WW + j1];
        f10 = lds[s1 * WW + j0];
        f11 = lds[s1 * WW + j1];
    } else {
        // exactness fallback: direct global gather
        f00 = im[i0 * WW + j0];
        f01 = im[i0 * WW + j1];
        f10 = im[i1 * WW + j0];
        f11 = im[i1 * WW + j1];
    }
    float f0 = f00 + (f01 - f00) * dj;
    float f1 = f10 + (f11 - f10) * dj;
    return f0 + (f1 - f0) * di;
}

__global__ __launch_bounds__(256) void SpatialWarp_kernel(
    const float* __restrict__ img,   // (B,H,W)
    const float* __restrict__ U,     // (B,T,H,W,2)
    float* __restrict__ out)         // (B,T,H,W)
{
    __shared__ float lds[NROWS * WW];          // 32 KB

    int bid = blockIdx.x;                      // = b*H + i
    int b = bid >> 9;
    int i = bid & (HH - 1);
    const float* im = img + (size_t)b * (HH * WW);

    int k = threadIdx.x;                       // pair index within row (0..255)
    int j = k << 1;
    float fi = (float)i;
    float fj0 = (float)j, fj1 = (float)(j + 1);

    // --- software-prefetch all 16 U rows for this (b,i) into registers ---
    vf4 uu[TT];
#pragma unroll
    for (int t = 0; t < TT; ++t) {
        size_t rowoff = (((size_t)b * TT + t) * HH + i) * WW;
        uu[t] = __builtin_nontemporal_load(
            reinterpret_cast<const vf4*>(U + rowoff * 2) + k);
    }

    // --- stage img rows clamp(i-7 .. i+8) into LDS (vec4, coalesced) ---
    for (int idx = threadIdx.x; idx < NROWS * (WW / 4); idx += 256) {
        int s = idx >> 7;            // / 128 vf4-per-row
        int c = idx & 127;
        int r = min(max(i - SLOT_OFF + s, 0), HH - 1);
        reinterpret_cast<vf4*>(lds)[idx] =
            reinterpret_cast<const vf4*>(im + (size_t)r * WW)[c];
    }
    __syncthreads();

    // --- 16 time steps, gathers served from LDS ---
#pragma unroll
    for (int t = 0; t < TT; ++t) {
        size_t rowoff = (((size_t)b * TT + t) * HH + i) * WW;
        vf4 u = uu[t];
        float r0 = warp_one(lds, im, i, fi, fj0, u.x, u.y);
        float r1 = warp_one(lds, im, i, fi, fj1, u.z, u.w);
        vf2 rv; rv.x = r0; rv.y = r1;
        __builtin_nontemporal_store(rv, reinterpret_cast<vf2*>(out + rowoff) + k);
    }
}

extern "C" void kernel_launch(void* const* d_in, const int* in_sizes, int n_in,
                              void* d_out, int out_size, void* d_ws, size_t ws_size,
                              hipStream_t stream) {
    const float* img = (const float*)d_in[0];   // (8,512,512) fp32
    const float* U   = (const float*)d_in[1];   // (8,16,512,512,2) fp32
    float* out = (float*)d_out;                 // (8,16,512,512) fp32

    dim3 block(256);
    dim3 grid(8 * HH);                          // one block per (b, i) row
    hipLaunchKernelGGL(SpatialWarp_kernel, grid, block, 0, stream,
                       img, U, out);
}

// Round 4
// 82.406 us; speedup vs baseline: 1.8397x; 1.0724x over previous
//
#include <hip/hip_runtime.h>

// B=8, T=16, H=512, W=512
#define HH 512
#define WW 512
#define TT 16
#define ROWS 2        // output rows per block
#define NR 13         // staged img rows: clamp(ip-5 .. ip+7)
#define OFF 5

typedef float vf4 __attribute__((ext_vector_type(4)));
typedef float vf2 __attribute__((ext_vector_type(2)));

__device__ __forceinline__ float warp_one(const float* __restrict__ lds,
                                          const float* __restrict__ im,
                                          int ip, float fi, float fj,
                                          float ux, float uy) {
    float si = fi - ux;
    float sj = fj - uy;
    int i0 = (int)floorf(si);
    int j0 = (int)floorf(sj);
    i0 = min(max(i0, 0), HH - 1);
    j0 = min(max(j0, 0), WW - 1);
    int i1 = min(i0 + 1, HH - 1);
    int j1 = min(j0 + 1, WW - 1);
    // fractional weights from CLIPPED corners (matches reference)
    float di = si - (float)i0;
    float dj = sj - (float)j0;
    int s0 = i0 - ip + OFF;
    int s1 = i1 - ip + OFF;
    float f00, f01, f10, f11;
    if (((unsigned)s0 < NR) & ((unsigned)s1 < NR)) {
        // fast path: staged window (slot s holds img row ip-OFF+s, clamped —
        // consistent with clipped i0/i1 by construction)
        f00 = lds[s0 * WW + j0];
        f01 = lds[s0 * WW + j1];
        f10 = lds[s1 * WW + j0];
        f11 = lds[s1 * WW + j1];
    } else {
        // exactness fallback: direct global gather (rare, P ~ 1e-5/elem)
        f00 = im[i0 * WW + j0];
        f01 = im[i0 * WW + j1];
        f10 = im[i1 * WW + j0];
        f11 = im[i1 * WW + j1];
    }
    float f0 = f00 + (f01 - f00) * dj;
    float f1 = f10 + (f11 - f10) * dj;
    return f0 + (f1 - f0) * di;
}

__global__ __launch_bounds__(256) void SpatialWarp_kernel(
    const float* __restrict__ img,   // (B,H,W)
    const float* __restrict__ U,     // (B,T,H,W,2)
    float* __restrict__ out)         // (B,T,H,W)
{
    __shared__ float lds[NR * WW];             // 26 KB

    int bid = blockIdx.x;                      // = b*256 + row-pair
    int b  = bid >> 8;
    int ip = (bid & 255) << 1;                 // base output row (even)
    const float* im = img + (size_t)b * (HH * WW);

    int k = threadIdx.x;                       // column-pair index 0..255
    int j = k << 1;
    float fj0 = (float)j, fj1 = (float)(j + 1);
    float fi0 = (float)ip, fi1 = (float)(ip + 1);

    // U row offsets (in float4 units): row (t, ip+r) starts at
    // ((b*T + t)*H + ip + r) * W * 2 floats = ... /4 float4
    size_t ubase = (((size_t)b * TT) * HH + ip) * (WW / 2);  // float4 units, t=0
    const vf4* Uv = reinterpret_cast<const vf4*>(U);

    // prologue: load t=0's U for both rows (overlaps staging)
    vf4 u0c = __builtin_nontemporal_load(Uv + ubase + k);
    vf4 u1c = __builtin_nontemporal_load(Uv + ubase + (WW / 2) + k);

    // stage img rows clamp(ip-OFF .. ip-OFF+NR-1) into LDS (vec4, coalesced)
    for (int idx = threadIdx.x; idx < NR * (WW / 4); idx += 256) {
        int s = idx >> 7;            // / 128 vf4-per-row
        int c = idx & 127;
        int r = min(max(ip - OFF + s, 0), HH - 1);
        reinterpret_cast<vf4*>(lds)[idx] =
            reinterpret_cast<const vf4*>(im + (size_t)r * WW)[c];
    }
    __syncthreads();

    size_t ostride = (size_t)HH * WW;          // out floats per t step
#pragma unroll
    for (int t = 0; t < TT; ++t) {
        vf4 u0n, u1n;
        if (t < TT - 1) {
            size_t un = ubase + (size_t)(t + 1) * HH * (WW / 2);
            u0n = __builtin_nontemporal_load(Uv + un + k);
            u1n = __builtin_nontemporal_load(Uv + un + (WW / 2) + k);
        }
        float r00 = warp_one(lds, im, ip, fi0, fj0, u0c.x, u0c.y);
        float r01 = warp_one(lds, im, ip, fi0, fj1, u0c.z, u0c.w);
        float r10 = warp_one(lds, im, ip, fi1, fj0, u1c.x, u1c.y);
        float r11 = warp_one(lds, im, ip, fi1, fj1, u1c.z, u1c.w);

        size_t obase = (((size_t)b * TT + t) * HH + ip) * WW;
        vf2 rv0; rv0.x = r00; rv0.y = r01;
        vf2 rv1; rv1.x = r10; rv1.y = r11;
        __builtin_nontemporal_store(rv0, reinterpret_cast<vf2*>(out + obase) + k);
        __builtin_nontemporal_store(rv1, reinterpret_cast<vf2*>(out + obase + WW) + k);

        u0c = u0n; u1c = u1n;
    }
    (void)ostride;
}

extern "C" void kernel_launch(void* const* d_in, const int* in_sizes, int n_in,
                              void* d_out, int out_size, void* d_ws, size_t ws_size,
                              hipStream_t stream) {
    const float* img = (const float*)d_in[0];   // (8,512,512) fp32
    const float* U   = (const float*)d_in[1];   // (8,16,512,512,2) fp32
    float* out = (float*)d_out;                 // (8,16,512,512) fp32

    dim3 block(256);
    dim3 grid(8 * (HH / ROWS));                 // 2048 blocks: one per (b, row-pair)
    hipLaunchKernelGGL(SpatialWarp_kernel, grid, block, 0, stream,
                       img, U, out);
}